// Round 8
// baseline (160.107 us; speedup 1.0000x reference)
//
#include <hip/hip_runtime.h>

// ---------------------------------------------------------------------------
// UniversalBlockEncoder: algebraically folded attention pooling.
//
//   u_i = silu(W1 x_i + b1)                 (the only per-point nonlinearity)
//   s_h(i) = g_h . u_i + d_h    with g_h = W2^T (scale Wk_h^T q_h)
//   p = exp(s)  (scores O(3), f32-safe without max-subtraction)
//   T_h = sum_i p_h(i) u_i ,  l_h = sum_i p_h(i)
//   out = Wo ( Wv ( W2 (T/l) + b2 ) + bv ) + bo
//
// R15: wave DE-PHASING on the proven R10 body. Evidence: 5 structurally
//      different kernels all pin main at ~35-41us with every pipe <50%
//      busy; all counters exonerated individually. Remaining consistent
//      mechanism: all waves run byte-identical code from a synchronized
//      start -> phase-locked stalls (every wave hits the same exp2/lgkm
//      window simultaneously; SIMD idles at the common duty cycle ~40%).
//      Change: wave gwave processes j-chunks in rotated order
//      ((c + gwave) & 3), staggering stall windows across co-resident
//      waves. Sums reorder only (fp-safe). Inner 8 pairs stay
//      compile-time (immediate LDS offsets). Also: NR reciprocal
//      reverted to v_rcp (R14 proved NR neutral; rcp = shorter chain).
// ---------------------------------------------------------------------------

#define LOG2E 1.44269504088896340736f
#define NLN2  (-0.69314718055994530942f)

#if __has_builtin(__builtin_amdgcn_exp2f)
#define EXP2(x) __builtin_amdgcn_exp2f(x)
#else
#define EXP2(x) exp2f(x)
#endif
#if __has_builtin(__builtin_amdgcn_rcpf)
#define RCP(x) __builtin_amdgcn_rcpf(x)
#else
#define RCP(x) (1.0f / (x))
#endif

// LDS-only ordering within a wave (each wave touches only its own region;
// wave lockstep => lgkmcnt(0) is a sufficient producer-consumer barrier).
#define LDS_WAIT() asm volatile("s_waitcnt lgkmcnt(0)" ::: "memory")

typedef __attribute__((ext_vector_type(8))) __bf16 bf16x8;
typedef __attribute__((ext_vector_type(4))) float  f32x4;
typedef __attribute__((ext_vector_type(2))) float  f32x2;

__device__ __forceinline__ f32x2 fma2(f32x2 a, f32x2 b, f32x2 c) {
#if __has_builtin(__builtin_elementwise_fma)
    return __builtin_elementwise_fma(a, b, c);
#else
    return (f32x2){fmaf(a.x, b.x, c.x), fmaf(a.y, b.y, c.y)};
#endif
}

// workspace float offsets
#define WS_PK   0      // 32 pairs x 16 floats (pair-SoA constants)
#define WS_D    512    // 4           : log2e * d_h
#define WS_ACC  768    // NSLOT x SLOTSTRIDE: [0..3]=l_h, [4+h*64+j]=T'_h[j]
#define NSLOT      64
#define SLOTSTRIDE 272

#define NPTS       (1024 * 1024)
#define K1_BLOCKS  2048
#define K1_THREADS 128
#define WAVES_TOTAL (K1_BLOCKS * 2)                   // 4096
#define GROUPS_PER_WAVE ((NPTS / 64) / WAVES_TOTAL)   // 4

// per-wave LDS region (shorts): p[4 x 72] + u[64 x 72]
#define PW_SHORTS  288
#define UW_SHORTS  (64 * 72)
#define WAVE_SHORTS (PW_SHORTS + UW_SHORTS)  // 4896 shorts (9792 B)

__device__ __forceinline__ unsigned short to_bf16(float x) {
    return (unsigned short)((__float_as_uint(x) + 0x8000u) >> 16);
}

// ---------------------------------------------------------------------------
// Setup: 64 blocks x 64 threads. Every block redundantly computes q and a
// (coalesced); block j computes g[j][h] lane-per-d + shuffle reduce. All
// blocks cooperatively zero the accumulator slots.
__global__ void setup_kernel(const float* __restrict__ W1, const float* __restrict__ b1,
                             const float* __restrict__ W2, const float* __restrict__ b2,
                             const float* __restrict__ query,
                             const float* __restrict__ ipw, const float* __restrict__ ipb,
                             float* __restrict__ ws)
{
    __shared__ float qv[64], qs[64], as4[4][64];
    const int t = threadIdx.x;
    const int b = blockIdx.x;     // = output j

    for (int i = b * 64 + t; i < NSLOT * SLOTSTRIDE; i += 64 * 64)
        ws[WS_ACC + i] = 0.0f;

    qv[t] = query[t];
    __syncthreads();

    {
        float a = ipb[t];
        #pragma unroll
        for (int k = 0; k < 64; ++k) a = fmaf(ipw[t * 64 + k], qv[k], a);
        qs[t] = a;
    }
    __syncthreads();

    #pragma unroll
    for (int h = 0; h < 4; ++h) {
        float a = 0.0f;
        #pragma unroll
        for (int m = 0; m < 16; ++m)
            a = fmaf(ipw[(64 + h * 16 + m) * 64 + t], qs[h * 16 + m], a);
        as4[h][t] = 0.25f * a;
    }
    __syncthreads();

    const float w2 = W2[t * 64 + b];
    float g[4];
    #pragma unroll
    for (int h = 0; h < 4; ++h) {
        float v = as4[h][t] * w2;
        for (int m = 1; m < 64; m <<= 1) v += __shfl_xor(v, m);
        g[h] = v;
    }
    if (t == 0) {
        const int base = 16 * (b >> 1);
        const int sub  = b & 1;
        ws[WS_PK + base + 0  + sub] = -LOG2E * W1[2 * b];      // cx
        ws[WS_PK + base + 2  + sub] = -LOG2E * W1[2 * b + 1];  // cy
        ws[WS_PK + base + 4  + sub] = -LOG2E * b1[b];          // cz
        ws[WS_PK + base + 6  + sub] = 0.0f;                    // pad
        ws[WS_PK + base + 8  + sub] = -g[0];                   // -g: LOG2E*NLN2 fold
        ws[WS_PK + base + 10 + sub] = -g[1];
        ws[WS_PK + base + 12 + sub] = -g[2];
        ws[WS_PK + base + 14 + sub] = -g[3];
    }
    if (b == 0 && t < 4) {
        float d = 0.0f;
        #pragma unroll
        for (int c = 0; c < 64; ++c) d += as4[t][c] * b2[c];
        float qb = 0.0f;
        #pragma unroll
        for (int m = 0; m < 16; ++m) qb += qs[t * 16 + m] * ipb[64 + t * 16 + m];
        ws[WS_D + t] = LOG2E * (d + 0.25f * qb);
    }
}

// ---------------------------------------------------------------------------
// Main: 2 independent waves/block (own LDS regions; pure-lgkm waits).
// Phase 1 (lane = point): hidden units in PAIRS via packed f32 math,
// j-chunks processed in wave-rotated order (de-phasing). Phase 2: 8x
// mfma_f32_16x16x32_bf16 per group. Epilogue: per-wave transpose D via
// LDS; block-combine across the two waves; wave 0 issues coalesced atomics.
__global__ __launch_bounds__(K1_THREADS) void main_kernel(
        const float* __restrict__ rr, const float* __restrict__ ri,
        const float4* __restrict__ pk4,
        const float* __restrict__ dvec, float* __restrict__ accb)
{
    __shared__ __align__(16) unsigned short lds[2][WAVE_SHORTS];

    const int t    = threadIdx.x;
    const int lane = t & 63;
    const int w    = t >> 6;
    const int m    = lane & 15;
    const int q    = lane >> 4;

    unsigned short* pw = lds[w];               // p: [h][pt], stride 72
    unsigned short* uw = lds[w] + PW_SHORTS;   // u: [j][pt], stride 72

    const float d0 = dvec[0], d1 = dvec[1], d2 = dvec[2], d3 = dvec[3];

    const int gwave = blockIdx.x * 2 + w;
    const int rot4  = gwave & 3;               // per-wave chunk rotation
    float l0 = 0, l1 = 0, l2 = 0, l3 = 0;
    f32x4 acc[4];
    #pragma unroll
    for (int i = 0; i < 4; ++i) acc[i] = (f32x4){0.f, 0.f, 0.f, 0.f};

    // hoist ALL global loads to kernel entry
    float rv[GROUPS_PER_WAVE], iv[GROUPS_PER_WAVE];
    #pragma unroll
    for (int it = 0; it < GROUPS_PER_WAVE; ++it) {
        const int idx = (gwave + it * WAVES_TOTAL) * 64 + lane;
        rv[it] = rr[idx];
        iv[it] = ri[idx];
    }

    for (int it = 0; it < GROUPS_PER_WAVE; ++it) {
        const f32x2 r2 = {rv[it], rv[it]};
        const f32x2 i2 = {iv[it], iv[it]};

        // packed score partials; halves summed after the loop
        f32x2 s0v = {d0, 0.f}, s1v = {d1, 0.f}, s2v = {d2, 0.f}, s3v = {d3, 0.f};

        // j-chunks in wave-rotated order: chunk cc = ((c + rot4) & 3),
        // inner 8 pairs compile-time -> immediate LDS offsets, uniform
        // s_load bases per chunk. Same sums, staggered stall phases.
        #pragma unroll
        for (int c = 0; c < 4; ++c) {
            const int cc = ((c + rot4) & 3) * 8;   // runtime-uniform chunk base
            #pragma unroll
            for (int s = 0; s < 8; ++s) {
                const int jp = cc + s;
                const float4 A  = pk4[4 * jp + 0];   // {cx0,cx1,cy0,cy1}
                const float4 B  = pk4[4 * jp + 1];   // {cz0,cz1, 0, 0 }
                const float4 C  = pk4[4 * jp + 2];   // {g00,g01,g10,g11}
                const float4 Dv = pk4[4 * jp + 3];   // {g20,g21,g30,g31}

                const f32x2 cx = {A.x, A.y};
                const f32x2 cy = {A.z, A.w};
                const f32x2 cz = {B.x, B.y};

                const f32x2 zn = fma2(cx, r2, fma2(cy, i2, cz));     // -log2e * z
                const f32x2 e  = {EXP2(zn.x), EXP2(zn.y)};           // exp(-z)
                const f32x2 op = e + (f32x2){1.f, 1.f};
                const f32x2 rc = {RCP(op.x), RCP(op.y)};             // sigmoid(z)
                const f32x2 ub = zn * rc;            // = u / NLN2  (fold)

                s0v = fma2((f32x2){C.x,  C.y},  ub, s0v);
                s1v = fma2((f32x2){C.z,  C.w},  ub, s1v);
                s2v = fma2((f32x2){Dv.x, Dv.y}, ub, s2v);
                s3v = fma2((f32x2){Dv.z, Dv.w}, ub, s3v);

                uw[(2 * jp)     * 72 + lane] = to_bf16(ub.x);
                uw[(2 * jp + 1) * 72 + lane] = to_bf16(ub.y);
            }
        }
        const float p0 = EXP2(s0v.x + s0v.y), p1 = EXP2(s1v.x + s1v.y);
        const float p2 = EXP2(s2v.x + s2v.y), p3 = EXP2(s3v.x + s3v.y);
        l0 += p0; l1 += p1; l2 += p2; l3 += p3;
        pw[0 * 72 + lane] = to_bf16(p0);
        pw[1 * 72 + lane] = to_bf16(p1);
        pw[2 * 72 + lane] = to_bf16(p2);
        pw[3 * 72 + lane] = to_bf16(p3);
        LDS_WAIT();    // writes visible to this wave's reads

        // B-frags (p), shared across j-tiles
        const bf16x8 b0 = *(const bf16x8*)(pw + m * 72 + q * 8);
        const bf16x8 b1 = *(const bf16x8*)(pw + m * 72 + q * 8 + 32);
        #pragma unroll
        for (int tt = 0; tt < 4; ++tt) {
            const bf16x8 a0 = *(const bf16x8*)(uw + (16 * tt + m) * 72 + q * 8);
            const bf16x8 a1 = *(const bf16x8*)(uw + (16 * tt + m) * 72 + q * 8 + 32);
            acc[tt] = __builtin_amdgcn_mfma_f32_16x16x32_bf16(a0, b0, acc[tt], 0, 0, 0);
            acc[tt] = __builtin_amdgcn_mfma_f32_16x16x32_bf16(a1, b1, acc[tt], 0, 0, 0);
        }
        LDS_WAIT();    // reads done before next iteration's writes (WAR)
    }

    // l: lane-local partials -> wave reduce
    for (int mm = 1; mm < 64; mm <<= 1) {
        l0 += __shfl_xor(l0, mm);
        l1 += __shfl_xor(l1, mm);
        l2 += __shfl_xor(l2, mm);
        l3 += __shfl_xor(l3, mm);
    }

    // ---- epilogue: per-wave transpose D via LDS, then block-combine ----
    // D: row = q*4 + reg = j_local(16tt..), col = m = h (cols 4..15 garbage)
    // scr[h][j], stride 66: writes <=2-way banks, reads 2-way (both free).
    float* scr = (float*)uw;   // own wave's u region (>= 268 floats available)
    if (m < 4) {
        #pragma unroll
        for (int tt = 0; tt < 4; ++tt)
            #pragma unroll
            for (int reg = 0; reg < 4; ++reg)
                scr[m * 66 + 16 * tt + 4 * q + reg] = acc[tt][reg];
    }
    // wave 1 publishes its wave-reduced l values alongside its scr
    if (w == 1 && lane == 0) {
        scr[4 * 66 + 0] = l0;
        scr[4 * 66 + 1] = l1;
        scr[4 * 66 + 2] = l2;
        scr[4 * 66 + 3] = l3;
    }
    __syncthreads();   // wave 1's scr + l visible to wave 0

    if (w == 0) {
        const float* scr1 = (const float*)(lds[1] + PW_SHORTS);
        float Th[4];
        #pragma unroll
        for (int h = 0; h < 4; ++h)
            Th[h] = scr[h * 66 + lane] + scr1[h * 66 + lane];

        float* accS = accb + (blockIdx.x & (NSLOT - 1)) * SLOTSTRIDE;
        if (lane == 0) {
            atomicAdd(accS + 0, l0 + scr1[4 * 66 + 0]);
            atomicAdd(accS + 1, l1 + scr1[4 * 66 + 1]);
            atomicAdd(accS + 2, l2 + scr1[4 * 66 + 2]);
            atomicAdd(accS + 3, l3 + scr1[4 * 66 + 3]);
        }
        atomicAdd(accS + 4 + 0 * 64 + lane, Th[0]);
        atomicAdd(accS + 4 + 1 * 64 + lane, Th[1]);
        atomicAdd(accS + 4 + 2 * 64 + lane, Th[2]);
        atomicAdd(accS + 4 + 3 * 64 + lane, Th[3]);
    }
}

// ---------------------------------------------------------------------------
__global__ void finish_kernel(const float* __restrict__ W2, const float* __restrict__ b2,
                              const float* __restrict__ ipw, const float* __restrict__ ipb,
                              const float* __restrict__ opw, const float* __restrict__ opb,
                              const float* __restrict__ ws, float* __restrict__ out)
{
    __shared__ float red[260];   // [0..3]=l, [4+h*64+k]=T'
    __shared__ float sb[256];    // S-bar per (h, j)
    __shared__ float pl[64];     // pooled
    const int t = threadIdx.x;

    {
        float a = 0.0f;
        for (int s = 0; s < NSLOT; ++s) a += ws[WS_ACC + s * SLOTSTRIDE + t];
        red[t] = a;
        if (t < 4) {
            float a2 = 0.0f;
            for (int s = 0; s < NSLOT; ++s) a2 += ws[WS_ACC + s * SLOTSTRIDE + 256 + t];
            red[256 + t] = a2;
        }
    }
    __syncthreads();

    // S-bar_h[j] = W2[j][:] . (NLN2 * T'_h / l_h) + b2[j]
    {
        const int h = t >> 6, j = t & 63;
        const float inv = NLN2 / red[h];
        float a = 0.0f;
        #pragma unroll
        for (int k = 0; k < 64; ++k) a += W2[j * 64 + k] * red[4 + h * 64 + k];
        sb[t] = fmaf(inv, a, b2[j]);
    }
    __syncthreads();

    if (t < 64) {
        const int h = t >> 4;
        float a = ipb[128 + t];
        #pragma unroll
        for (int d = 0; d < 64; ++d) a += ipw[(128 + t) * 64 + d] * sb[h * 64 + d];
        pl[t] = a;
    }
    __syncthreads();

    if (t < 64) {
        float a = opb[t];
        #pragma unroll
        for (int p = 0; p < 64; ++p) a += opw[t * 64 + p] * pl[p];
        out[t] = a;
    }
}

// ---------------------------------------------------------------------------
extern "C" void kernel_launch(void* const* d_in, const int* in_sizes, int n_in,
                              void* d_out, int out_size, void* d_ws, size_t ws_size,
                              hipStream_t stream)
{
    const float* rr  = (const float*)d_in[0];   // rho_real
    const float* ri  = (const float*)d_in[1];   // rho_imag
    // d_in[2..5]: l_A, l_B, Z_A, Z_B — unused by the reference
    const float* W1  = (const float*)d_in[6];
    const float* b1  = (const float*)d_in[7];
    const float* W2  = (const float*)d_in[8];
    const float* b2  = (const float*)d_in[9];
    const float* qy  = (const float*)d_in[10];
    const float* ipw = (const float*)d_in[11];
    const float* ipb = (const float*)d_in[12];
    const float* opw = (const float*)d_in[13];
    const float* opb = (const float*)d_in[14];
    float* ws  = (float*)d_ws;
    float* out = (float*)d_out;

    setup_kernel<<<64, 64, 0, stream>>>(W1, b1, W2, b2, qy, ipw, ipb, ws);
    main_kernel<<<K1_BLOCKS, K1_THREADS, 0, stream>>>(
        rr, ri,
        (const float4*)(ws + WS_PK),
        ws + WS_D, ws + WS_ACC);
    finish_kernel<<<1, 256, 0, stream>>>(W2, b2, ipw, ipb, opw, opb, ws, out);
}

// Round 9
// 129.213 us; speedup vs baseline: 1.2391x; 1.2391x over previous
//
#include <hip/hip_runtime.h>

// ---------------------------------------------------------------------------
// UniversalBlockEncoder: algebraically folded attention pooling.
//
//   u_i = silu(W1 x_i + b1)                 (the only per-point nonlinearity)
//   s_h(i) = g_h . u_i + d_h    with g_h = W2^T (scale Wk_h^T q_h)
//   p = exp(s)  (scores O(3), f32-safe without max-subtraction)
//   T_h = sum_i p_h(i) u_i ,  l_h = sum_i p_h(i)
//   out = Wo ( Wv ( W2 (T/l) + b2 ) + bv ) + bo
//
// R16: 2-points-per-lane ILP on the proven R10 body. Evidence: R10-R14
//      show no pipe saturated and wave count (14..32/CU) irrelevant ->
//      per-wave dependency stalls dominate (busy ~40%). R15's de-phasing
//      failed on VGPR blowup (runtime indices -> 256 VGPR); this round
//      doubles ILP with ALL indices compile-time: each iteration loads
//      the constant pair once and runs TWO independent sigmoid->score
//      chains (points A,B from two 64-pt groups). Halves constant
//      s_loads and per-group overhead; MFMA total unchanged (32/wave,
//      same acc). LDS doubles to 19.6KB/wave -> 4 blocks/CU = 8 waves/CU
//      (R13 proved wave count is slack). Inner unroll 4 keeps the
//      register window equal to R10's proven 8x1pt.
// ---------------------------------------------------------------------------

#define LOG2E 1.44269504088896340736f
#define NLN2  (-0.69314718055994530942f)

#if __has_builtin(__builtin_amdgcn_exp2f)
#define EXP2(x) __builtin_amdgcn_exp2f(x)
#else
#define EXP2(x) exp2f(x)
#endif
#if __has_builtin(__builtin_amdgcn_rcpf)
#define RCP(x) __builtin_amdgcn_rcpf(x)
#else
#define RCP(x) (1.0f / (x))
#endif

// LDS-only ordering within a wave (each wave touches only its own region;
// wave lockstep => lgkmcnt(0) is a sufficient producer-consumer barrier).
#define LDS_WAIT() asm volatile("s_waitcnt lgkmcnt(0)" ::: "memory")

typedef __attribute__((ext_vector_type(8))) __bf16 bf16x8;
typedef __attribute__((ext_vector_type(4))) float  f32x4;
typedef __attribute__((ext_vector_type(2))) float  f32x2;

__device__ __forceinline__ f32x2 fma2(f32x2 a, f32x2 b, f32x2 c) {
#if __has_builtin(__builtin_elementwise_fma)
    return __builtin_elementwise_fma(a, b, c);
#else
    return (f32x2){fmaf(a.x, b.x, c.x), fmaf(a.y, b.y, c.y)};
#endif
}

// workspace float offsets
#define WS_PK   0      // 32 pairs x 16 floats (pair-SoA constants)
#define WS_D    512    // 4           : log2e * d_h
#define WS_ACC  768    // NSLOT x SLOTSTRIDE: [0..3]=l_h, [4+h*64+j]=T'_h[j]
#define NSLOT      64
#define SLOTSTRIDE 272

#define NPTS       (1024 * 1024)
#define K1_BLOCKS  2048
#define K1_THREADS 128
#define WAVES_TOTAL (K1_BLOCKS * 2)                   // 4096
#define ITERS      2   // x 2 points/lane = 4 groups/wave (same coverage as R10)

// per-wave LDS region (shorts): two halves, each p[4 x 72] + u[64 x 72]
#define PW_SHORTS   288
#define UW_SHORTS   (64 * 72)
#define HALF_SHORTS (PW_SHORTS + UW_SHORTS)   // 4896
#define WAVE_SHORTS (2 * HALF_SHORTS)         // 9792 shorts (19584 B)

__device__ __forceinline__ unsigned short to_bf16(float x) {
    return (unsigned short)((__float_as_uint(x) + 0x8000u) >> 16);
}

// ---------------------------------------------------------------------------
// Setup: 64 blocks x 64 threads. Every block redundantly computes q and a
// (coalesced); block j computes g[j][h] lane-per-d + shuffle reduce. All
// blocks cooperatively zero the accumulator slots.
__global__ void setup_kernel(const float* __restrict__ W1, const float* __restrict__ b1,
                             const float* __restrict__ W2, const float* __restrict__ b2,
                             const float* __restrict__ query,
                             const float* __restrict__ ipw, const float* __restrict__ ipb,
                             float* __restrict__ ws)
{
    __shared__ float qv[64], qs[64], as4[4][64];
    const int t = threadIdx.x;
    const int b = blockIdx.x;     // = output j

    for (int i = b * 64 + t; i < NSLOT * SLOTSTRIDE; i += 64 * 64)
        ws[WS_ACC + i] = 0.0f;

    qv[t] = query[t];
    __syncthreads();

    {
        float a = ipb[t];
        #pragma unroll
        for (int k = 0; k < 64; ++k) a = fmaf(ipw[t * 64 + k], qv[k], a);
        qs[t] = a;
    }
    __syncthreads();

    #pragma unroll
    for (int h = 0; h < 4; ++h) {
        float a = 0.0f;
        #pragma unroll
        for (int m = 0; m < 16; ++m)
            a = fmaf(ipw[(64 + h * 16 + m) * 64 + t], qs[h * 16 + m], a);
        as4[h][t] = 0.25f * a;
    }
    __syncthreads();

    const float w2 = W2[t * 64 + b];
    float g[4];
    #pragma unroll
    for (int h = 0; h < 4; ++h) {
        float v = as4[h][t] * w2;
        for (int m = 1; m < 64; m <<= 1) v += __shfl_xor(v, m);
        g[h] = v;
    }
    if (t == 0) {
        const int base = 16 * (b >> 1);
        const int sub  = b & 1;
        ws[WS_PK + base + 0  + sub] = -LOG2E * W1[2 * b];      // cx
        ws[WS_PK + base + 2  + sub] = -LOG2E * W1[2 * b + 1];  // cy
        ws[WS_PK + base + 4  + sub] = -LOG2E * b1[b];          // cz
        ws[WS_PK + base + 6  + sub] = 0.0f;                    // pad
        ws[WS_PK + base + 8  + sub] = -g[0];                   // -g: LOG2E*NLN2 fold
        ws[WS_PK + base + 10 + sub] = -g[1];
        ws[WS_PK + base + 12 + sub] = -g[2];
        ws[WS_PK + base + 14 + sub] = -g[3];
    }
    if (b == 0 && t < 4) {
        float d = 0.0f;
        #pragma unroll
        for (int c = 0; c < 64; ++c) d += as4[t][c] * b2[c];
        float qb = 0.0f;
        #pragma unroll
        for (int m = 0; m < 16; ++m) qb += qs[t * 16 + m] * ipb[64 + t * 16 + m];
        ws[WS_D + t] = LOG2E * (d + 0.25f * qb);
    }
}

// ---------------------------------------------------------------------------
// Main: 2 independent waves/block (own LDS regions; pure-lgkm waits).
// Phase 1 (lane = 2 points A,B): per constant pair, TWO independent packed
// sigmoid->score chains. Phase 2: 16x mfma per iteration (A-half + B-half
// into the same acc). Epilogue: per-wave transpose D via LDS; block-combine
// across the two waves; wave 0 issues coalesced atomics.
__global__ __launch_bounds__(K1_THREADS) void main_kernel(
        const float* __restrict__ rr, const float* __restrict__ ri,
        const float4* __restrict__ pk4,
        const float* __restrict__ dvec, float* __restrict__ accb)
{
    __shared__ __align__(16) unsigned short lds[2][WAVE_SHORTS];

    const int t    = threadIdx.x;
    const int lane = t & 63;
    const int w    = t >> 6;
    const int m    = lane & 15;
    const int q    = lane >> 4;

    unsigned short* pwA = lds[w];                             // p(A): [h][pt]
    unsigned short* uwA = lds[w] + PW_SHORTS;                 // u(A): [j][pt]
    unsigned short* pwB = lds[w] + HALF_SHORTS;               // p(B)
    unsigned short* uwB = lds[w] + HALF_SHORTS + PW_SHORTS;   // u(B)

    const float d0 = dvec[0], d1 = dvec[1], d2 = dvec[2], d3 = dvec[3];

    const int gwave = blockIdx.x * 2 + w;
    float l0 = 0, l1 = 0, l2 = 0, l3 = 0;
    f32x4 acc[4];
    #pragma unroll
    for (int i = 0; i < 4; ++i) acc[i] = (f32x4){0.f, 0.f, 0.f, 0.f};

    for (int it = 0; it < ITERS; ++it) {
        // two point-groups per iteration (same coverage as R10's 4 groups)
        const int idxA = (gwave + (2 * it)     * WAVES_TOTAL) * 64 + lane;
        const int idxB = (gwave + (2 * it + 1) * WAVES_TOTAL) * 64 + lane;
        const float rA = rr[idxA], iA = ri[idxA];
        const float rB = rr[idxB], iB = ri[idxB];
        const f32x2 r2A = {rA, rA}, i2A = {iA, iA};
        const f32x2 r2B = {rB, rB}, i2B = {iB, iB};

        // packed score partials, one set per point; halves summed after loop
        f32x2 sA0 = {d0, 0.f}, sA1 = {d1, 0.f}, sA2 = {d2, 0.f}, sA3 = {d3, 0.f};
        f32x2 sB0 = {d0, 0.f}, sB1 = {d1, 0.f}, sB2 = {d2, 0.f}, sB3 = {d3, 0.f};

        #pragma unroll 4
        for (int jp = 0; jp < 32; ++jp) {
            const float4 A  = pk4[4 * jp + 0];   // {cx0,cx1,cy0,cy1} wave-uniform
            const float4 B  = pk4[4 * jp + 1];   // {cz0,cz1, 0, 0 }
            const float4 C  = pk4[4 * jp + 2];   // {g00,g01,g10,g11}
            const float4 Dv = pk4[4 * jp + 3];   // {g20,g21,g30,g31}

            const f32x2 cx = {A.x, A.y};
            const f32x2 cy = {A.z, A.w};
            const f32x2 cz = {B.x, B.y};

            // chain A
            const f32x2 znA = fma2(cx, r2A, fma2(cy, i2A, cz));
            const f32x2 eA  = {EXP2(znA.x), EXP2(znA.y)};
            const f32x2 opA = eA + (f32x2){1.f, 1.f};
            const f32x2 rcA = {RCP(opA.x), RCP(opA.y)};
            const f32x2 ubA = znA * rcA;
            // chain B (independent)
            const f32x2 znB = fma2(cx, r2B, fma2(cy, i2B, cz));
            const f32x2 eB  = {EXP2(znB.x), EXP2(znB.y)};
            const f32x2 opB = eB + (f32x2){1.f, 1.f};
            const f32x2 rcB = {RCP(opB.x), RCP(opB.y)};
            const f32x2 ubB = znB * rcB;

            sA0 = fma2((f32x2){C.x,  C.y},  ubA, sA0);
            sA1 = fma2((f32x2){C.z,  C.w},  ubA, sA1);
            sA2 = fma2((f32x2){Dv.x, Dv.y}, ubA, sA2);
            sA3 = fma2((f32x2){Dv.z, Dv.w}, ubA, sA3);
            sB0 = fma2((f32x2){C.x,  C.y},  ubB, sB0);
            sB1 = fma2((f32x2){C.z,  C.w},  ubB, sB1);
            sB2 = fma2((f32x2){Dv.x, Dv.y}, ubB, sB2);
            sB3 = fma2((f32x2){Dv.z, Dv.w}, ubB, sB3);

            uwA[(2 * jp)     * 72 + lane] = to_bf16(ubA.x);
            uwA[(2 * jp + 1) * 72 + lane] = to_bf16(ubA.y);
            uwB[(2 * jp)     * 72 + lane] = to_bf16(ubB.x);
            uwB[(2 * jp + 1) * 72 + lane] = to_bf16(ubB.y);
        }
        const float pA0 = EXP2(sA0.x + sA0.y), pA1 = EXP2(sA1.x + sA1.y);
        const float pA2 = EXP2(sA2.x + sA2.y), pA3 = EXP2(sA3.x + sA3.y);
        const float pB0 = EXP2(sB0.x + sB0.y), pB1 = EXP2(sB1.x + sB1.y);
        const float pB2 = EXP2(sB2.x + sB2.y), pB3 = EXP2(sB3.x + sB3.y);
        l0 += pA0 + pB0; l1 += pA1 + pB1; l2 += pA2 + pB2; l3 += pA3 + pB3;
        pwA[0 * 72 + lane] = to_bf16(pA0);
        pwA[1 * 72 + lane] = to_bf16(pA1);
        pwA[2 * 72 + lane] = to_bf16(pA2);
        pwA[3 * 72 + lane] = to_bf16(pA3);
        pwB[0 * 72 + lane] = to_bf16(pB0);
        pwB[1 * 72 + lane] = to_bf16(pB1);
        pwB[2 * 72 + lane] = to_bf16(pB2);
        pwB[3 * 72 + lane] = to_bf16(pB3);
        LDS_WAIT();    // writes visible to this wave's reads

        // B-frags (p), shared across j-tiles; rows m>=4 read garbage ->
        // contaminates only D cols >=4, never read (same as R10)
        const bf16x8 bA0 = *(const bf16x8*)(pwA + m * 72 + q * 8);
        const bf16x8 bA1 = *(const bf16x8*)(pwA + m * 72 + q * 8 + 32);
        const bf16x8 bB0 = *(const bf16x8*)(pwB + m * 72 + q * 8);
        const bf16x8 bB1 = *(const bf16x8*)(pwB + m * 72 + q * 8 + 32);
        #pragma unroll
        for (int tt = 0; tt < 4; ++tt) {
            const bf16x8 aA0 = *(const bf16x8*)(uwA + (16 * tt + m) * 72 + q * 8);
            const bf16x8 aA1 = *(const bf16x8*)(uwA + (16 * tt + m) * 72 + q * 8 + 32);
            acc[tt] = __builtin_amdgcn_mfma_f32_16x16x32_bf16(aA0, bA0, acc[tt], 0, 0, 0);
            acc[tt] = __builtin_amdgcn_mfma_f32_16x16x32_bf16(aA1, bA1, acc[tt], 0, 0, 0);
            const bf16x8 aB0 = *(const bf16x8*)(uwB + (16 * tt + m) * 72 + q * 8);
            const bf16x8 aB1 = *(const bf16x8*)(uwB + (16 * tt + m) * 72 + q * 8 + 32);
            acc[tt] = __builtin_amdgcn_mfma_f32_16x16x32_bf16(aB0, bB0, acc[tt], 0, 0, 0);
            acc[tt] = __builtin_amdgcn_mfma_f32_16x16x32_bf16(aB1, bB1, acc[tt], 0, 0, 0);
        }
        LDS_WAIT();    // reads done before next iteration's writes (WAR)
    }

    // l: lane-local partials -> wave reduce
    for (int mm = 1; mm < 64; mm <<= 1) {
        l0 += __shfl_xor(l0, mm);
        l1 += __shfl_xor(l1, mm);
        l2 += __shfl_xor(l2, mm);
        l3 += __shfl_xor(l3, mm);
    }

    // ---- epilogue: per-wave transpose D via LDS, then block-combine ----
    // D: row = q*4 + reg = j_local(16tt..), col = m = h (cols 4..15 garbage)
    // scr[h][j], stride 66: writes <=2-way banks, reads 2-way (both free).
    float* scr = (float*)uwA;   // own wave's uA region (>= 268 floats free)
    if (m < 4) {
        #pragma unroll
        for (int tt = 0; tt < 4; ++tt)
            #pragma unroll
            for (int reg = 0; reg < 4; ++reg)
                scr[m * 66 + 16 * tt + 4 * q + reg] = acc[tt][reg];
    }
    // wave 1 publishes its wave-reduced l values alongside its scr
    if (w == 1 && lane == 0) {
        scr[4 * 66 + 0] = l0;
        scr[4 * 66 + 1] = l1;
        scr[4 * 66 + 2] = l2;
        scr[4 * 66 + 3] = l3;
    }
    __syncthreads();   // wave 1's scr + l visible to wave 0

    if (w == 0) {
        const float* scr1 = (const float*)(lds[1] + PW_SHORTS);
        float Th[4];
        #pragma unroll
        for (int h = 0; h < 4; ++h)
            Th[h] = scr[h * 66 + lane] + scr1[h * 66 + lane];

        float* accS = accb + (blockIdx.x & (NSLOT - 1)) * SLOTSTRIDE;
        if (lane == 0) {
            atomicAdd(accS + 0, l0 + scr1[4 * 66 + 0]);
            atomicAdd(accS + 1, l1 + scr1[4 * 66 + 1]);
            atomicAdd(accS + 2, l2 + scr1[4 * 66 + 2]);
            atomicAdd(accS + 3, l3 + scr1[4 * 66 + 3]);
        }
        atomicAdd(accS + 4 + 0 * 64 + lane, Th[0]);
        atomicAdd(accS + 4 + 1 * 64 + lane, Th[1]);
        atomicAdd(accS + 4 + 2 * 64 + lane, Th[2]);
        atomicAdd(accS + 4 + 3 * 64 + lane, Th[3]);
    }
}

// ---------------------------------------------------------------------------
__global__ void finish_kernel(const float* __restrict__ W2, const float* __restrict__ b2,
                              const float* __restrict__ ipw, const float* __restrict__ ipb,
                              const float* __restrict__ opw, const float* __restrict__ opb,
                              const float* __restrict__ ws, float* __restrict__ out)
{
    __shared__ float red[260];   // [0..3]=l, [4+h*64+k]=T'
    __shared__ float sb[256];    // S-bar per (h, j)
    __shared__ float pl[64];     // pooled
    const int t = threadIdx.x;

    {
        float a = 0.0f;
        for (int s = 0; s < NSLOT; ++s) a += ws[WS_ACC + s * SLOTSTRIDE + t];
        red[t] = a;
        if (t < 4) {
            float a2 = 0.0f;
            for (int s = 0; s < NSLOT; ++s) a2 += ws[WS_ACC + s * SLOTSTRIDE + 256 + t];
            red[256 + t] = a2;
        }
    }
    __syncthreads();

    // S-bar_h[j] = W2[j][:] . (NLN2 * T'_h / l_h) + b2[j]
    {
        const int h = t >> 6, j = t & 63;
        const float inv = NLN2 / red[h];
        float a = 0.0f;
        #pragma unroll
        for (int k = 0; k < 64; ++k) a += W2[j * 64 + k] * red[4 + h * 64 + k];
        sb[t] = fmaf(inv, a, b2[j]);
    }
    __syncthreads();

    if (t < 64) {
        const int h = t >> 4;
        float a = ipb[128 + t];
        #pragma unroll
        for (int d = 0; d < 64; ++d) a += ipw[(128 + t) * 64 + d] * sb[h * 64 + d];
        pl[t] = a;
    }
    __syncthreads();

    if (t < 64) {
        float a = opb[t];
        #pragma unroll
        for (int p = 0; p < 64; ++p) a += opw[t * 64 + p] * pl[p];
        out[t] = a;
    }
}

// ---------------------------------------------------------------------------
extern "C" void kernel_launch(void* const* d_in, const int* in_sizes, int n_in,
                              void* d_out, int out_size, void* d_ws, size_t ws_size,
                              hipStream_t stream)
{
    const float* rr  = (const float*)d_in[0];   // rho_real
    const float* ri  = (const float*)d_in[1];   // rho_imag
    // d_in[2..5]: l_A, l_B, Z_A, Z_B — unused by the reference
    const float* W1  = (const float*)d_in[6];
    const float* b1  = (const float*)d_in[7];
    const float* W2  = (const float*)d_in[8];
    const float* b2  = (const float*)d_in[9];
    const float* qy  = (const float*)d_in[10];
    const float* ipw = (const float*)d_in[11];
    const float* ipb = (const float*)d_in[12];
    const float* opw = (const float*)d_in[13];
    const float* opb = (const float*)d_in[14];
    float* ws  = (float*)d_ws;
    float* out = (float*)d_out;

    setup_kernel<<<64, 64, 0, stream>>>(W1, b1, W2, b2, qy, ipw, ipb, ws);
    main_kernel<<<K1_BLOCKS, K1_THREADS, 0, stream>>>(
        rr, ri,
        (const float4*)(ws + WS_PK),
        ws + WS_D, ws + WS_ACC);
    finish_kernel<<<1, 256, 0, stream>>>(W2, b2, ipw, ipb, opw, opb, ws, out);
}

// Round 10
// 122.220 us; speedup vs baseline: 1.3100x; 1.0572x over previous
//
#include <hip/hip_runtime.h>

// ---------------------------------------------------------------------------
// UniversalBlockEncoder: algebraically folded attention pooling.
//
//   u_i = silu(W1 x_i + b1)                 (the only per-point nonlinearity)
//   s_h(i) = g_h . u_i + d_h    with g_h = W2^T (scale Wk_h^T q_h)
//   p = exp(s)  (scores O(3), f32-safe without max-subtraction)
//   T_h = sum_i p_h(i) u_i ,  l_h = sum_i p_h(i)
//   out = Wo ( Wv ( W2 (T/l) + b2 ) + bv ) + bo
//
// R17: TERMINAL REVERT to the best-measured variant (R10, 121.73us).
//      Falsification matrix complete (R8 VALU, R10 atomics, R11 K$,
//      R13 occupancy, R14 trans, R16 ILP: all neutral; main pinned at
//      36-42us across 5 structures with all pipes <40% busy). Total is
//      dominated by two harness workspace fills at ~6.6 TB/s (at the
//      achievable HBM ceiling). No further kernel-side lever identified
//      with positive expected value.
// ---------------------------------------------------------------------------

#define LOG2E 1.44269504088896340736f
#define NLN2  (-0.69314718055994530942f)

#if __has_builtin(__builtin_amdgcn_exp2f)
#define EXP2(x) __builtin_amdgcn_exp2f(x)
#else
#define EXP2(x) exp2f(x)
#endif
#if __has_builtin(__builtin_amdgcn_rcpf)
#define RCP(x) __builtin_amdgcn_rcpf(x)
#else
#define RCP(x) (1.0f / (x))
#endif

// LDS-only ordering within a wave (each wave touches only its own region;
// wave lockstep => lgkmcnt(0) is a sufficient producer-consumer barrier).
#define LDS_WAIT() asm volatile("s_waitcnt lgkmcnt(0)" ::: "memory")

typedef __attribute__((ext_vector_type(8))) __bf16 bf16x8;
typedef __attribute__((ext_vector_type(4))) float  f32x4;
typedef __attribute__((ext_vector_type(2))) float  f32x2;

__device__ __forceinline__ f32x2 fma2(f32x2 a, f32x2 b, f32x2 c) {
#if __has_builtin(__builtin_elementwise_fma)
    return __builtin_elementwise_fma(a, b, c);
#else
    return (f32x2){fmaf(a.x, b.x, c.x), fmaf(a.y, b.y, c.y)};
#endif
}

// workspace float offsets
#define WS_PK   0      // 32 pairs x 16 floats (pair-SoA constants)
#define WS_D    512    // 4           : log2e * d_h
#define WS_ACC  768    // NSLOT x SLOTSTRIDE: [0..3]=l_h, [4+h*64+j]=T'_h[j]
#define NSLOT      64
#define SLOTSTRIDE 272

#define NPTS       (1024 * 1024)
#define K1_BLOCKS  2048
#define K1_THREADS 128
#define WAVES_TOTAL (K1_BLOCKS * 2)                   // 4096
#define GROUPS_PER_WAVE ((NPTS / 64) / WAVES_TOTAL)   // 4

// per-wave LDS region (shorts): p[4 x 72] + u[64 x 72]
#define PW_SHORTS  288
#define UW_SHORTS  (64 * 72)
#define WAVE_SHORTS (PW_SHORTS + UW_SHORTS)  // 4896 shorts (9792 B)

__device__ __forceinline__ unsigned short to_bf16(float x) {
    return (unsigned short)((__float_as_uint(x) + 0x8000u) >> 16);
}

// ---------------------------------------------------------------------------
// Setup: 64 blocks x 64 threads. Every block redundantly computes q and a
// (coalesced); block j computes g[j][h] lane-per-d + shuffle reduce. All
// blocks cooperatively zero the accumulator slots.
__global__ void setup_kernel(const float* __restrict__ W1, const float* __restrict__ b1,
                             const float* __restrict__ W2, const float* __restrict__ b2,
                             const float* __restrict__ query,
                             const float* __restrict__ ipw, const float* __restrict__ ipb,
                             float* __restrict__ ws)
{
    __shared__ float qv[64], qs[64], as4[4][64];
    const int t = threadIdx.x;
    const int b = blockIdx.x;     // = output j

    for (int i = b * 64 + t; i < NSLOT * SLOTSTRIDE; i += 64 * 64)
        ws[WS_ACC + i] = 0.0f;

    qv[t] = query[t];
    __syncthreads();

    {
        float a = ipb[t];
        #pragma unroll
        for (int k = 0; k < 64; ++k) a = fmaf(ipw[t * 64 + k], qv[k], a);
        qs[t] = a;
    }
    __syncthreads();

    #pragma unroll
    for (int h = 0; h < 4; ++h) {
        float a = 0.0f;
        #pragma unroll
        for (int m = 0; m < 16; ++m)
            a = fmaf(ipw[(64 + h * 16 + m) * 64 + t], qs[h * 16 + m], a);
        as4[h][t] = 0.25f * a;
    }
    __syncthreads();

    const float w2 = W2[t * 64 + b];
    float g[4];
    #pragma unroll
    for (int h = 0; h < 4; ++h) {
        float v = as4[h][t] * w2;
        for (int m = 1; m < 64; m <<= 1) v += __shfl_xor(v, m);
        g[h] = v;
    }
    if (t == 0) {
        const int base = 16 * (b >> 1);
        const int sub  = b & 1;
        ws[WS_PK + base + 0  + sub] = -LOG2E * W1[2 * b];      // cx
        ws[WS_PK + base + 2  + sub] = -LOG2E * W1[2 * b + 1];  // cy
        ws[WS_PK + base + 4  + sub] = -LOG2E * b1[b];          // cz
        ws[WS_PK + base + 6  + sub] = 0.0f;                    // pad
        ws[WS_PK + base + 8  + sub] = -g[0];                   // -g: LOG2E*NLN2 fold
        ws[WS_PK + base + 10 + sub] = -g[1];
        ws[WS_PK + base + 12 + sub] = -g[2];
        ws[WS_PK + base + 14 + sub] = -g[3];
    }
    if (b == 0 && t < 4) {
        float d = 0.0f;
        #pragma unroll
        for (int c = 0; c < 64; ++c) d += as4[t][c] * b2[c];
        float qb = 0.0f;
        #pragma unroll
        for (int m = 0; m < 16; ++m) qb += qs[t * 16 + m] * ipb[64 + t * 16 + m];
        ws[WS_D + t] = LOG2E * (d + 0.25f * qb);
    }
}

// ---------------------------------------------------------------------------
// Main: 2 independent waves/block (own LDS regions; pure-lgkm waits).
// Phase 1 (lane = point): hidden units in PAIRS via packed f32 math.
// Phase 2: 8x mfma_f32_16x16x32_bf16 per group:
//   D[j-tile(16) x h] += A(u)[m=j][k=pt] * B(p)[k=pt][n=h]
// (B rows n>=4 garbage -> contaminates only D cols >=4, never read.)
// Epilogue: per-wave transpose D via LDS; block-combine across the two
// waves (one __syncthreads); wave 0 issues the (coalesced) atomics.
__global__ __launch_bounds__(K1_THREADS) void main_kernel(
        const float* __restrict__ rr, const float* __restrict__ ri,
        const float4* __restrict__ pk4,
        const float* __restrict__ dvec, float* __restrict__ accb)
{
    __shared__ __align__(16) unsigned short lds[2][WAVE_SHORTS];

    const int t    = threadIdx.x;
    const int lane = t & 63;
    const int w    = t >> 6;
    const int m    = lane & 15;
    const int q    = lane >> 4;

    unsigned short* pw = lds[w];               // p: [h][pt], stride 72
    unsigned short* uw = lds[w] + PW_SHORTS;   // u: [j][pt], stride 72

    const float d0 = dvec[0], d1 = dvec[1], d2 = dvec[2], d3 = dvec[3];

    const int gwave = blockIdx.x * 2 + w;
    float l0 = 0, l1 = 0, l2 = 0, l3 = 0;
    f32x4 acc[4];
    #pragma unroll
    for (int i = 0; i < 4; ++i) acc[i] = (f32x4){0.f, 0.f, 0.f, 0.f};

    // hoist ALL global loads to kernel entry
    float rv[GROUPS_PER_WAVE], iv[GROUPS_PER_WAVE];
    #pragma unroll
    for (int it = 0; it < GROUPS_PER_WAVE; ++it) {
        const int idx = (gwave + it * WAVES_TOTAL) * 64 + lane;
        rv[it] = rr[idx];
        iv[it] = ri[idx];
    }

    for (int it = 0; it < GROUPS_PER_WAVE; ++it) {
        const f32x2 r2 = {rv[it], rv[it]};
        const f32x2 i2 = {iv[it], iv[it]};

        // packed score partials; halves summed after the loop
        f32x2 s0v = {d0, 0.f}, s1v = {d1, 0.f}, s2v = {d2, 0.f}, s3v = {d3, 0.f};

        #pragma unroll 8
        for (int jp = 0; jp < 32; ++jp) {
            const float4 A  = pk4[4 * jp + 0];   // {cx0,cx1,cy0,cy1} wave-uniform
            const float4 B  = pk4[4 * jp + 1];   // {cz0,cz1, 0, 0 }
            const float4 C  = pk4[4 * jp + 2];   // {g00,g01,g10,g11}
            const float4 Dv = pk4[4 * jp + 3];   // {g20,g21,g30,g31}

            const f32x2 cx = {A.x, A.y};
            const f32x2 cy = {A.z, A.w};
            const f32x2 cz = {B.x, B.y};

            const f32x2 zn = fma2(cx, r2, fma2(cy, i2, cz));     // -log2e * z
            const f32x2 e  = {EXP2(zn.x), EXP2(zn.y)};           // exp(-z)
            const f32x2 op = e + (f32x2){1.f, 1.f};
            const f32x2 rc = {RCP(op.x), RCP(op.y)};             // sigmoid(z)
            const f32x2 ub = zn * rc;            // = u / NLN2  (fold)

            s0v = fma2((f32x2){C.x,  C.y},  ub, s0v);
            s1v = fma2((f32x2){C.z,  C.w},  ub, s1v);
            s2v = fma2((f32x2){Dv.x, Dv.y}, ub, s2v);
            s3v = fma2((f32x2){Dv.z, Dv.w}, ub, s3v);

            uw[(2 * jp)     * 72 + lane] = to_bf16(ub.x);
            uw[(2 * jp + 1) * 72 + lane] = to_bf16(ub.y);
        }
        const float p0 = EXP2(s0v.x + s0v.y), p1 = EXP2(s1v.x + s1v.y);
        const float p2 = EXP2(s2v.x + s2v.y), p3 = EXP2(s3v.x + s3v.y);
        l0 += p0; l1 += p1; l2 += p2; l3 += p3;
        pw[0 * 72 + lane] = to_bf16(p0);
        pw[1 * 72 + lane] = to_bf16(p1);
        pw[2 * 72 + lane] = to_bf16(p2);
        pw[3 * 72 + lane] = to_bf16(p3);
        LDS_WAIT();    // writes visible to this wave's reads

        // B-frags (p), shared across j-tiles
        const bf16x8 b0 = *(const bf16x8*)(pw + m * 72 + q * 8);
        const bf16x8 b1 = *(const bf16x8*)(pw + m * 72 + q * 8 + 32);
        #pragma unroll
        for (int tt = 0; tt < 4; ++tt) {
            const bf16x8 a0 = *(const bf16x8*)(uw + (16 * tt + m) * 72 + q * 8);
            const bf16x8 a1 = *(const bf16x8*)(uw + (16 * tt + m) * 72 + q * 8 + 32);
            acc[tt] = __builtin_amdgcn_mfma_f32_16x16x32_bf16(a0, b0, acc[tt], 0, 0, 0);
            acc[tt] = __builtin_amdgcn_mfma_f32_16x16x32_bf16(a1, b1, acc[tt], 0, 0, 0);
        }
        LDS_WAIT();    // reads done before next iteration's writes (WAR)
    }

    // l: lane-local partials -> wave reduce
    for (int mm = 1; mm < 64; mm <<= 1) {
        l0 += __shfl_xor(l0, mm);
        l1 += __shfl_xor(l1, mm);
        l2 += __shfl_xor(l2, mm);
        l3 += __shfl_xor(l3, mm);
    }

    // ---- epilogue: per-wave transpose D via LDS, then block-combine ----
    // D: row = q*4 + reg = j_local(16tt..), col = m = h (cols 4..15 garbage)
    // scr[h][j], stride 66: writes <=2-way banks, reads 2-way (both free).
    float* scr = (float*)uw;   // own wave's u region (>= 268 floats available)
    if (m < 4) {
        #pragma unroll
        for (int tt = 0; tt < 4; ++tt)
            #pragma unroll
            for (int reg = 0; reg < 4; ++reg)
                scr[m * 66 + 16 * tt + 4 * q + reg] = acc[tt][reg];
    }
    // wave 1 publishes its wave-reduced l values alongside its scr
    if (w == 1 && lane == 0) {
        scr[4 * 66 + 0] = l0;
        scr[4 * 66 + 1] = l1;
        scr[4 * 66 + 2] = l2;
        scr[4 * 66 + 3] = l3;
    }
    __syncthreads();   // wave 1's scr + l visible to wave 0

    if (w == 0) {
        const float* scr1 = (const float*)(lds[1] + PW_SHORTS);
        float Th[4];
        #pragma unroll
        for (int h = 0; h < 4; ++h)
            Th[h] = scr[h * 66 + lane] + scr1[h * 66 + lane];

        float* accS = accb + (blockIdx.x & (NSLOT - 1)) * SLOTSTRIDE;
        if (lane == 0) {
            atomicAdd(accS + 0, l0 + scr1[4 * 66 + 0]);
            atomicAdd(accS + 1, l1 + scr1[4 * 66 + 1]);
            atomicAdd(accS + 2, l2 + scr1[4 * 66 + 2]);
            atomicAdd(accS + 3, l3 + scr1[4 * 66 + 3]);
        }
        atomicAdd(accS + 4 + 0 * 64 + lane, Th[0]);
        atomicAdd(accS + 4 + 1 * 64 + lane, Th[1]);
        atomicAdd(accS + 4 + 2 * 64 + lane, Th[2]);
        atomicAdd(accS + 4 + 3 * 64 + lane, Th[3]);
    }
}

// ---------------------------------------------------------------------------
__global__ void finish_kernel(const float* __restrict__ W2, const float* __restrict__ b2,
                              const float* __restrict__ ipw, const float* __restrict__ ipb,
                              const float* __restrict__ opw, const float* __restrict__ opb,
                              const float* __restrict__ ws, float* __restrict__ out)
{
    __shared__ float red[260];   // [0..3]=l, [4+h*64+k]=T'
    __shared__ float sb[256];    // S-bar per (h, j)
    __shared__ float pl[64];     // pooled
    const int t = threadIdx.x;

    {
        float a = 0.0f;
        for (int s = 0; s < NSLOT; ++s) a += ws[WS_ACC + s * SLOTSTRIDE + t];
        red[t] = a;
        if (t < 4) {
            float a2 = 0.0f;
            for (int s = 0; s < NSLOT; ++s) a2 += ws[WS_ACC + s * SLOTSTRIDE + 256 + t];
            red[256 + t] = a2;
        }
    }
    __syncthreads();

    // S-bar_h[j] = W2[j][:] . (NLN2 * T'_h / l_h) + b2[j]
    {
        const int h = t >> 6, j = t & 63;
        const float inv = NLN2 / red[h];
        float a = 0.0f;
        #pragma unroll
        for (int k = 0; k < 64; ++k) a += W2[j * 64 + k] * red[4 + h * 64 + k];
        sb[t] = fmaf(inv, a, b2[j]);
    }
    __syncthreads();

    if (t < 64) {
        const int h = t >> 4;
        float a = ipb[128 + t];
        #pragma unroll
        for (int d = 0; d < 64; ++d) a += ipw[(128 + t) * 64 + d] * sb[h * 64 + d];
        pl[t] = a;
    }
    __syncthreads();

    if (t < 64) {
        float a = opb[t];
        #pragma unroll
        for (int p = 0; p < 64; ++p) a += opw[t * 64 + p] * pl[p];
        out[t] = a;
    }
}

// ---------------------------------------------------------------------------
extern "C" void kernel_launch(void* const* d_in, const int* in_sizes, int n_in,
                              void* d_out, int out_size, void* d_ws, size_t ws_size,
                              hipStream_t stream)
{
    const float* rr  = (const float*)d_in[0];   // rho_real
    const float* ri  = (const float*)d_in[1];   // rho_imag
    // d_in[2..5]: l_A, l_B, Z_A, Z_B — unused by the reference
    const float* W1  = (const float*)d_in[6];
    const float* b1  = (const float*)d_in[7];
    const float* W2  = (const float*)d_in[8];
    const float* b2  = (const float*)d_in[9];
    const float* qy  = (const float*)d_in[10];
    const float* ipw = (const float*)d_in[11];
    const float* ipb = (const float*)d_in[12];
    const float* opw = (const float*)d_in[13];
    const float* opb = (const float*)d_in[14];
    float* ws  = (float*)d_ws;
    float* out = (float*)d_out;

    setup_kernel<<<64, 64, 0, stream>>>(W1, b1, W2, b2, qy, ipw, ipb, ws);
    main_kernel<<<K1_BLOCKS, K1_THREADS, 0, stream>>>(
        rr, ri,
        (const float4*)(ws + WS_PK),
        ws + WS_D, ws + WS_ACC);
    finish_kernel<<<1, 256, 0, stream>>>(W2, b2, ipw, ipb, opw, opb, ws, out);
}